// Round 6
// baseline (123.416 us; speedup 1.0000x reference)
//
#include <hip/hip_runtime.h>
#include <hip/hip_bf16.h>

typedef unsigned short ushort;
typedef unsigned int uint;
typedef __bf16 bf16x8 __attribute__((ext_vector_type(8)));
typedef float f32x4 __attribute__((ext_vector_type(4)));
typedef uint uint4v __attribute__((ext_vector_type(4)));
typedef uint uint2v __attribute__((ext_vector_type(2)));

#define CI 128
#define HIN 64
#define WIN 64
#define CO 256
#define HO 62
#define WO 62
#define NB 32
#define KTOT 1152            // 9 taps * 128 ci  (k = tap*128 + ci, repacked)
#define PIXIMG 3844          // 62*62
#define NPIX 123008          // 32*3844 = 128*961
#define XIMG 524288
#define NKT 18               // 1152/64 K-tiles

__device__ __forceinline__ ushort f2bf(float f) {
  uint u = __builtin_bit_cast(uint, f);
  u += 0x7fffu + ((u >> 16) & 1u);   // RNE
  return (ushort)(u >> 16);
}

// ---------------- prep: w[co][ci][3][3] fp32 -> w2[co][tap*128+ci] bf16 ----------------
__global__ void repack_w_kernel(const float* __restrict__ w, ushort* __restrict__ w2) {
  const int co = blockIdx.x;
  for (int idx = threadIdx.x; idx < KTOT; idx += 256) {
    const int t  = idx >> 7;
    const int ci = idx & 127;
    w2[co * KTOT + idx] = f2bf(w[(co * CI + ci) * 9 + t]);
  }
}

// ---------------- prep: x[n][ci][h][w] fp32 -> x2[n][h][w][ci] bf16 ----------------
#define XPAD 132
__global__ __launch_bounds__(256) void repack_x_kernel(const float* __restrict__ x,
                                                       ushort* __restrict__ x2) {
  __shared__ float t[WIN * XPAD];
  const int n = blockIdx.y;
  const int h = blockIdx.x;
  const int tid = threadIdx.x;
  const float* src = x + ((size_t)n * CI * HIN + h) * WIN;
  #pragma unroll
  for (int it = 0; it < 8; ++it) {
    const int idx = it * 256 + tid;
    const int ci  = idx >> 4;
    const int w4  = (idx & 15) * 4;
    const float4 v = *reinterpret_cast<const float4*>(src + (size_t)ci * (HIN * WIN) + w4);
    t[(w4 + 0) * XPAD + ci] = v.x;
    t[(w4 + 1) * XPAD + ci] = v.y;
    t[(w4 + 2) * XPAD + ci] = v.z;
    t[(w4 + 3) * XPAD + ci] = v.w;
  }
  __syncthreads();
  ushort* dst = x2 + ((size_t)(n * HIN + h) * WIN) * CI;
  #pragma unroll
  for (int it = 0; it < 4; ++it) {
    const int idx = it * 256 + tid;
    const int w   = idx >> 4;
    const int cig = idx & 15;
    const float* p = &t[w * XPAD + cig * 8];
    uint4v q;
    q[0] = (uint)f2bf(p[0]) | ((uint)f2bf(p[1]) << 16);
    q[1] = (uint)f2bf(p[2]) | ((uint)f2bf(p[3]) << 16);
    q[2] = (uint)f2bf(p[4]) | ((uint)f2bf(p[5]) << 16);
    q[3] = (uint)f2bf(p[6]) | ((uint)f2bf(p[7]) << 16);
    *reinterpret_cast<uint4v*>(dst + (size_t)w * CI + cig * 8) = q;
  }
}

// ======================= main: 256x256x64 8-phase counted-vmcnt ========================
// LDS: 2 dbuf x [slot0 B-h0 | slot1 A-h0 | slot2 B-h1 | slot3 A-h1], slot = 128rows x 64 bf16
// swizzle: phys_chunk = logical_chunk ^ (row&7)  (16B chunks, pre-swizzled global source)
// Stage discipline: every STAGE targets a slot whose last ds_read drained before the
// PRECEDING barrier (lgkmcnt(0) runs before each closing barrier) -> no WAR race.

#define GLOAD(SRC, DSTOFF) \
  __builtin_amdgcn_global_load_lds( \
      (const __attribute__((address_space(1))) uint*)(const void*)(SRC), \
      (__attribute__((address_space(3))) uint*)(void*)&lds[DSTOFF], 16, 0, 0)

#define STAGE_A(DB, SLOT, KT) do { \
  const int _ca = (KT) * 64; \
  GLOAD(w2 + aOff[(SLOT) >> 1][0] + _ca, (DB) + (SLOT) * 8192 + stgu);       \
  GLOAD(w2 + aOff[(SLOT) >> 1][1] + _ca, (DB) + (SLOT) * 8192 + stgu + 512); \
} while (0)

#define STAGE_B(DB, SLOT, KT) do { \
  const int _tp = (KT) >> 1; \
  const int _rr = (_tp * 11) >> 5; \
  const int _cb = (_rr * WIN + (_tp - _rr * 3)) * CI + ((KT) & 1) * 64; \
  GLOAD(x2 + bOff[(SLOT) >> 1][0] + _cb, (DB) + (SLOT) * 8192 + stgu);       \
  GLOAD(x2 + bOff[(SLOT) >> 1][1] + _cb, (DB) + (SLOT) * 8192 + stgu + 512); \
} while (0)

#define PH_LOADS(LDB, ASLOT, BSLOT) do { \
  _Pragma("unroll") for (int mf = 0; mf < 4; ++mf) { \
    fa0[mf] = *reinterpret_cast<const bf16x8*>(&lds[(LDB) + (ASLOT) * 8192 + arow + mf * 1024 + ck0]); \
    fa1[mf] = *reinterpret_cast<const bf16x8*>(&lds[(LDB) + (ASLOT) * 8192 + arow + mf * 1024 + ck1]); } \
  _Pragma("unroll") for (int nf = 0; nf < 2; ++nf) { \
    fb0[nf] = *reinterpret_cast<const bf16x8*>(&lds[(LDB) + (BSLOT) * 8192 + brow + nf * 1024 + ck0]); \
    fb1[nf] = *reinterpret_cast<const bf16x8*>(&lds[(LDB) + (BSLOT) * 8192 + brow + nf * 1024 + ck1]); } \
} while (0)

#define PH_MMA(MG, NG) do { \
  __builtin_amdgcn_s_barrier(); \
  asm volatile("s_waitcnt lgkmcnt(0)" ::: "memory"); \
  __builtin_amdgcn_s_setprio(1); \
  _Pragma("unroll") for (int mf = 0; mf < 4; ++mf) \
    _Pragma("unroll") for (int nf = 0; nf < 2; ++nf) { \
      acc[(MG) * 4 + mf][(NG) * 2 + nf] = __builtin_amdgcn_mfma_f32_16x16x32_bf16( \
          fa0[mf], fb0[nf], acc[(MG) * 4 + mf][(NG) * 2 + nf], 0, 0, 0); \
      acc[(MG) * 4 + mf][(NG) * 2 + nf] = __builtin_amdgcn_mfma_f32_16x16x32_bf16( \
          fa1[mf], fb1[nf], acc[(MG) * 4 + mf][(NG) * 2 + nf], 0, 0, 0); } \
  __builtin_amdgcn_s_setprio(0); \
  __builtin_amdgcn_s_barrier(); \
} while (0)

__global__ __launch_bounds__(512, 2)
void conv_8ph_kernel(const ushort* __restrict__ x2, const ushort* __restrict__ w2,
                     float* __restrict__ out)
{
  __shared__ alignas(16) ushort lds[65536];   // 128 KiB

  const int tid  = threadIdx.x;
  const int lane = tid & 63;
  const int wid  = tid >> 6;    // 0..7
  const int wm   = wid >> 2;    // 0..1  (co 64-half within slot)
  const int wn   = wid & 3;     // 0..3  (pixel 32-quarter within slot)

  const int p0 = blockIdx.x * 256;   // pixel tile (481 tiles; last is half-valid)

  // staging lane geometry (dest is wave-uniform; HW adds lane*16B)
  const int lrow = lane >> 3;              // row within 8-row group
  const int lc   = (lane & 7) ^ lrow;      // pre-swizzled logical chunk
  const int stgu = wid * 1024;             // wave-uniform LDS dest (ushort units)

  // A source offsets: rows h*128 + wid*16 + j*8 + lrow
  int aOff[2][2];
  #pragma unroll
  for (int h = 0; h < 2; ++h)
    #pragma unroll
    for (int j = 0; j < 2; ++j)
      aOff[h][j] = (h * 128 + wid * 16 + j * 8 + lrow) * KTOT + lc * 8;

  // B source offsets, pixel rows clamped for tail tile
  int bOff[2][2];
  #pragma unroll
  for (int h = 0; h < 2; ++h)
    #pragma unroll
    for (int j = 0; j < 2; ++j) {
      int pglob = p0 + h * 128 + wid * 16 + j * 8 + lrow;
      pglob = pglob < NPIX ? pglob : (NPIX - 1);
      const int nimg = pglob / PIXIMG;
      const int prem = pglob - nimg * PIXIMG;
      const int oh   = prem / WO;
      const int ow   = prem - oh * WO;
      bOff[h][j] = ((nimg * HIN + oh) * WIN + ow) * CI + lc * 8;
    }

  // fragment read bases (swizzle folded via XOR with lane&7)
  const int arow = (wm * 64 + (lane & 15)) * 64;
  const int brow = (wn * 32 + (lane & 15)) * 64;
  const int ck0  = ((lane >> 4) ^ (lane & 7)) * 8;
  const int ck1  = ((4 + (lane >> 4)) ^ (lane & 7)) * 8;

  f32x4 acc[8][4];
  #pragma unroll
  for (int i = 0; i < 8; ++i)
    #pragma unroll
    for (int j = 0; j < 4; ++j)
      acc[i][j] = (f32x4){0.f, 0.f, 0.f, 0.f};

  bf16x8 fa0[4], fa1[4], fb0[2], fb1[2];

  // ---- prologue: t0 full (8 loads) + t1's B-h0,A-h0 (4 loads) ----
  STAGE_B(0, 0, 0);
  STAGE_A(0, 1, 0);
  STAGE_B(0, 2, 0);
  STAGE_A(0, 3, 0);
  STAGE_B(32768, 0, 1);
  STAGE_A(32768, 1, 1);
  asm volatile("s_waitcnt vmcnt(4)" ::: "memory");   // t0's 4 slots landed
  __builtin_amdgcn_s_barrier();

  int ldb = 0;
  #pragma unroll 1
  for (int t = 0; t < 16; ++t) {
    // p1: q(A-h0,B-h0); stage t+1's B-h1,A-h1 -> other dbuf (slots idle since prev p4)
    PH_LOADS(ldb, 1, 0);
    STAGE_B(ldb ^ 32768, 2, t + 1);
    STAGE_A(ldb ^ 32768, 3, t + 1);
    PH_MMA(0, 0);
    // p2: q(A-h1,B-h0); no stage
    PH_LOADS(ldb, 3, 0);
    PH_MMA(1, 0);
    // p3: q(A-h0,B-h1); stage t+2's B-h0 -> slot0 (last read p2, barrier-separated)
    PH_LOADS(ldb, 1, 2);
    STAGE_B(ldb, 0, t + 2);
    PH_MMA(0, 1);
    // p4: q(A-h1,B-h1); stage t+2's A-h0 -> slot1 (last read p3); counted wait
    PH_LOADS(ldb, 3, 2);
    STAGE_A(ldb, 1, t + 2);
    asm volatile("s_waitcnt vmcnt(4)" ::: "memory");  // tile t+1 fully landed
    PH_MMA(1, 1);
    ldb ^= 32768;
  }
  // ---- t = 16: stage only t17's B-h1,A-h1 at p1; drain at p4 ----
  PH_LOADS(ldb, 1, 0);
  STAGE_B(ldb ^ 32768, 2, 17);
  STAGE_A(ldb ^ 32768, 3, 17);
  PH_MMA(0, 0);
  PH_LOADS(ldb, 3, 0);
  PH_MMA(1, 0);
  PH_LOADS(ldb, 1, 2);
  PH_MMA(0, 1);
  PH_LOADS(ldb, 3, 2);
  asm volatile("s_waitcnt vmcnt(0)" ::: "memory");    // tile 17 fully landed
  PH_MMA(1, 1);
  ldb ^= 32768;
  // ---- t = 17: no staging, no waits ----
  PH_LOADS(ldb, 1, 0);
  PH_MMA(0, 0);
  PH_LOADS(ldb, 3, 0);
  PH_MMA(1, 0);
  PH_LOADS(ldb, 1, 2);
  PH_MMA(0, 1);
  PH_LOADS(ldb, 3, 2);
  PH_MMA(1, 1);

  // ---- epilogue: co = MG*128 + wm*64 + mf*16 + (lane>>4)*4 + r ; pix = p0 + NG*128 + wn*32 + nf*16 + (lane&15)
  #pragma unroll
  for (int ni = 0; ni < 4; ++ni) {
    const int pix = p0 + (ni >> 1) * 128 + wn * 32 + (ni & 1) * 16 + (lane & 15);
    if (pix < NPIX) {
      const int n2  = pix / PIXIMG;
      const int pr2 = pix - n2 * PIXIMG;
      float* ob = out + (size_t)n2 * (CO * PIXIMG) + pr2;
      #pragma unroll
      for (int mi = 0; mi < 8; ++mi) {
        const int cobase = (mi >> 2) * 128 + wm * 64 + (mi & 3) * 16 + ((lane >> 4) * 4);
        float* po = ob + (size_t)cobase * PIXIMG;
        #pragma unroll
        for (int r = 0; r < 4; ++r)
          po[(size_t)r * PIXIMG] = acc[mi][ni][r];
      }
    }
  }
}

// ---------------- fallback (tiny workspace): direct fp32 gather, reg-staged ----------------
__global__ __launch_bounds__(256, 3)
void conv_fallback_kernel(const float* __restrict__ x, const float* __restrict__ wt,
                          float* __restrict__ out)
{
  __shared__ alignas(16) ushort a_lds[128 * 64];
  __shared__ alignas(16) ushort b_lds[128 * 64];

  const int tid  = threadIdx.x;
  const int lane = tid & 63;
  const int wid  = tid >> 6;
  const int wrow = wid >> 1;
  const int wcol = wid & 1;
  const int co0 = blockIdx.x * 128;
  const int p0  = blockIdx.y * 128;

  const int pl    = tid & 127;
  const int kgsel = __builtin_amdgcn_readfirstlane(tid >> 7);
  const int pglob = p0 + pl;
  const int nimg  = pglob / PIXIMG;
  const int prem  = pglob - nimg * PIXIMG;
  const int oh    = prem / WO;
  const int ow    = prem - oh * WO;
  const int xpix  = nimg * XIMG + oh * WIN + ow;

  const int frow_a = wrow * 64 + (lane & 15);
  const int frow_b = wcol * 64 + (lane & 15);
  int aoff[2], boff[2];
  #pragma unroll
  for (int kk = 0; kk < 2; ++kk) {
    const int chk = (kk * 4 + (lane >> 4)) ^ (lane & 7);
    aoff[kk] = frow_a * 64 + chk * 8;
    boff[kk] = frow_b * 64 + chk * 8;
  }

  f32x4 acc[4][4];
  #pragma unroll
  for (int i = 0; i < 4; ++i)
    #pragma unroll
    for (int j = 0; j < 4; ++j)
      acc[i][j] = (f32x4){0.f, 0.f, 0.f, 0.f};

  for (int kt = 0; kt < NKT; ++kt) {
    const int k0 = kt * 64;
    if (kt) __syncthreads();

    #pragma unroll
    for (int it = 0; it < 4; ++it) {
      const int kg = kgsel + it * 2;
      uint pk[4];
      #pragma unroll
      for (int j = 0; j < 8; ++j) {
        const int k  = k0 + kg * 8 + j;
        const int ci = k / 9;
        const int rs = k - ci * 9;
        const int r  = rs / 3;
        const int s  = rs - r * 3;
        const ushort u = f2bf(x[xpix + ci * (HIN * WIN) + r * WIN + s]);
        if (j & 1) pk[j >> 1] |= ((uint)u) << 16;
        else       pk[j >> 1]  = (uint)u;
      }
      uint4v q = {pk[0], pk[1], pk[2], pk[3]};
      *reinterpret_cast<uint4v*>(&b_lds[pl * 64 + ((kg ^ (pl & 7)) * 8)]) = q;
    }

    #pragma unroll
    for (int i = 0; i < 8; ++i) {
      const int id  = i * 256 + tid;
      const int row = id >> 4;
      const int c4  = id & 15;
      const float4 v = *reinterpret_cast<const float4*>(
          wt + (size_t)(co0 + row) * KTOT + k0 + c4 * 4);
      uint2v q;
      q[0] = (uint)f2bf(v.x) | ((uint)f2bf(v.y) << 16);
      q[1] = (uint)f2bf(v.z) | ((uint)f2bf(v.w) << 16);
      *reinterpret_cast<uint2v*>(
          &a_lds[row * 64 + (((c4 >> 1) ^ (row & 7)) * 8) + (c4 & 1) * 4]) = q;
    }

    __syncthreads();

    #pragma unroll
    for (int kk = 0; kk < 2; ++kk) {
      bf16x8 af[4], bb[4];
      #pragma unroll
      for (int mi = 0; mi < 4; ++mi)
        af[mi] = *reinterpret_cast<const bf16x8*>(&a_lds[aoff[kk] + mi * (16 * 64)]);
      #pragma unroll
      for (int ni = 0; ni < 4; ++ni)
        bb[ni] = *reinterpret_cast<const bf16x8*>(&b_lds[boff[kk] + ni * (16 * 64)]);
      #pragma unroll
      for (int mi = 0; mi < 4; ++mi)
        #pragma unroll
        for (int ni = 0; ni < 4; ++ni)
          acc[mi][ni] = __builtin_amdgcn_mfma_f32_16x16x32_bf16(af[mi], bb[ni], acc[mi][ni], 0, 0, 0);
    }
  }

  #pragma unroll
  for (int ni = 0; ni < 4; ++ni) {
    const int pix = p0 + wcol * 64 + ni * 16 + (lane & 15);
    const int n2  = pix / PIXIMG;
    const int pr2 = pix - n2 * PIXIMG;
    float* ob = out + (size_t)n2 * (CO * PIXIMG) + pr2
                    + (size_t)(co0 + wrow * 64 + ((lane >> 4) * 4)) * PIXIMG;
    #pragma unroll
    for (int mi = 0; mi < 4; ++mi) {
      float* po = ob + (size_t)mi * (16 * PIXIMG);
      #pragma unroll
      for (int r = 0; r < 4; ++r)
        po[(size_t)r * PIXIMG] = acc[mi][ni][r];
    }
  }
}

extern "C" void kernel_launch(void* const* d_in, const int* in_sizes, int n_in,
                              void* d_out, int out_size, void* d_ws, size_t ws_size,
                              hipStream_t stream) {
  const float* x  = (const float*)d_in[0];
  const float* wt = (const float*)d_in[1];
  float* out = (float*)d_out;

  ushort* w2 = (ushort*)d_ws;
  ushort* x2 = (ushort*)((char*)d_ws + 589824);

  const size_t need = 589824 + (size_t)NB * XIMG * 2;   // ~34.1 MB

  if (ws_size >= need) {
    repack_w_kernel<<<dim3(CO), dim3(256), 0, stream>>>(wt, w2);
    repack_x_kernel<<<dim3(HIN, NB), dim3(256), 0, stream>>>(x, x2);
    conv_8ph_kernel<<<dim3(481), dim3(512), 0, stream>>>(x2, w2, out);
  } else {
    conv_fallback_kernel<<<dim3(CO / 128, NPIX / 128), dim3(256), 0, stream>>>(x, wt, out);
  }
}

// Round 7
// 113.889 us; speedup vs baseline: 1.0836x; 1.0836x over previous
//
#include <hip/hip_runtime.h>
#include <hip/hip_bf16.h>

typedef unsigned short ushort;
typedef unsigned int uint;
typedef __bf16 bf16x8 __attribute__((ext_vector_type(8)));
typedef float f32x4 __attribute__((ext_vector_type(4)));
typedef uint uint4v __attribute__((ext_vector_type(4)));
typedef uint uint2v __attribute__((ext_vector_type(2)));

#define CI 128
#define HIN 64
#define WIN 64
#define CO 256
#define HO 62
#define WO 62
#define NB 32
#define KTOT 1152            // 9 taps * 128 ci  (k = tap*128 + ci, repacked)
#define PIXIMG 3844          // 62*62
#define NPIX 123008          // 32*3844 = 128*961
#define XIMG 524288
#define NKT 18               // 1152/64 K-tiles

__device__ __forceinline__ ushort f2bf(float f) {
  uint u = __builtin_bit_cast(uint, f);
  u += 0x7fffu + ((u >> 16) & 1u);   // RNE
  return (ushort)(u >> 16);
}

// ---------------- prep: w[co][ci][3][3] fp32 -> w2[co][tap*128+ci] bf16 ----------------
__global__ void repack_w_kernel(const float* __restrict__ w, ushort* __restrict__ w2) {
  const int co = blockIdx.x;
  for (int idx = threadIdx.x; idx < KTOT; idx += 256) {
    const int t  = idx >> 7;
    const int ci = idx & 127;
    w2[co * KTOT + idx] = f2bf(w[(co * CI + ci) * 9 + t]);
  }
}

// ---------------- prep: x[n][ci][h][w] fp32 -> x2[n][h][w][ci] bf16 ----------------
#define XPAD 132
__global__ __launch_bounds__(256) void repack_x_kernel(const float* __restrict__ x,
                                                       ushort* __restrict__ x2) {
  __shared__ float t[WIN * XPAD];
  const int n = blockIdx.y;
  const int h = blockIdx.x;
  const int tid = threadIdx.x;
  const float* src = x + ((size_t)n * CI * HIN + h) * WIN;
  #pragma unroll
  for (int it = 0; it < 8; ++it) {
    const int idx = it * 256 + tid;
    const int ci  = idx >> 4;
    const int w4  = (idx & 15) * 4;
    const float4 v = *reinterpret_cast<const float4*>(src + (size_t)ci * (HIN * WIN) + w4);
    t[(w4 + 0) * XPAD + ci] = v.x;
    t[(w4 + 1) * XPAD + ci] = v.y;
    t[(w4 + 2) * XPAD + ci] = v.z;
    t[(w4 + 3) * XPAD + ci] = v.w;
  }
  __syncthreads();
  ushort* dst = x2 + ((size_t)(n * HIN + h) * WIN) * CI;
  #pragma unroll
  for (int it = 0; it < 4; ++it) {
    const int idx = it * 256 + tid;
    const int w   = idx >> 4;
    const int cig = idx & 15;
    const float* p = &t[w * XPAD + cig * 8];
    uint4v q;
    q[0] = (uint)f2bf(p[0]) | ((uint)f2bf(p[1]) << 16);
    q[1] = (uint)f2bf(p[2]) | ((uint)f2bf(p[3]) << 16);
    q[2] = (uint)f2bf(p[4]) | ((uint)f2bf(p[5]) << 16);
    q[3] = (uint)f2bf(p[6]) | ((uint)f2bf(p[7]) << 16);
    *reinterpret_cast<uint4v*>(dst + (size_t)w * CI + cig * 8) = q;
  }
}

// ======================= main: 256x256x64 8-phase, full register reuse =================
// LDS: 2 dbuf x [slot0 B-h0 | slot1 A-h0 | slot2 B-h1 | slot3 A-h1], slot = 128rows x 64 bf16
// swizzle: phys_chunk = logical_chunk ^ (row&7)  (16B chunks, pre-swizzled global source)
// Phase plan per K-tile (each fragment read from LDS exactly ONCE, held in regs):
//   p1: read A0+B0, stage t+1 B1,A1 -> other ; MFMA q(0,0)
//   p2: read A1,    stage t+2 B0,A0 -> cur   ; MFMA q(1,0)   (cur.s0/s1 data already in regs)
//   p3: read B1                               ; MFMA q(0,1)
//   p4: (no reads)  vmcnt(4) = t+1 landed     ; MFMA q(1,1)

#define GLOAD(SRC, DSTOFF) \
  __builtin_amdgcn_global_load_lds( \
      (const __attribute__((address_space(1))) uint*)(const void*)(SRC), \
      (__attribute__((address_space(3))) uint*)(void*)&lds[DSTOFF], 16, 0, 0)

#define STAGE_A(DB, SLOT, KT) do { \
  const int _ca = (KT) * 64; \
  GLOAD(w2 + aOff[(SLOT) >> 1][0] + _ca, (DB) + (SLOT) * 8192 + stgu);       \
  GLOAD(w2 + aOff[(SLOT) >> 1][1] + _ca, (DB) + (SLOT) * 8192 + stgu + 512); \
} while (0)

#define STAGE_B(DB, SLOT, KT) do { \
  const int _tp = (KT) >> 1; \
  const int _rr = (_tp * 11) >> 5; \
  const int _cb = (_rr * WIN + (_tp - _rr * 3)) * CI + ((KT) & 1) * 64; \
  GLOAD(x2 + bOff[(SLOT) >> 1][0] + _cb, (DB) + (SLOT) * 8192 + stgu);       \
  GLOAD(x2 + bOff[(SLOT) >> 1][1] + _cb, (DB) + (SLOT) * 8192 + stgu + 512); \
} while (0)

#define LOAD_A(F0, F1, LDB, SLOT) do { \
  _Pragma("unroll") for (int mf = 0; mf < 4; ++mf) { \
    F0[mf] = *reinterpret_cast<const bf16x8*>(&lds[(LDB) + (SLOT) * 8192 + arow + mf * 1024 + ck0]); \
    F1[mf] = *reinterpret_cast<const bf16x8*>(&lds[(LDB) + (SLOT) * 8192 + arow + mf * 1024 + ck1]); } \
} while (0)

#define LOAD_B(F0, F1, LDB, SLOT) do { \
  _Pragma("unroll") for (int nf = 0; nf < 2; ++nf) { \
    F0[nf] = *reinterpret_cast<const bf16x8*>(&lds[(LDB) + (SLOT) * 8192 + brow + nf * 1024 + ck0]); \
    F1[nf] = *reinterpret_cast<const bf16x8*>(&lds[(LDB) + (SLOT) * 8192 + brow + nf * 1024 + ck1]); } \
} while (0)

#define MMA(MG, NG, FA0, FA1, FB0, FB1) do { \
  __builtin_amdgcn_s_barrier(); \
  asm volatile("s_waitcnt lgkmcnt(0)" ::: "memory"); \
  __builtin_amdgcn_s_setprio(1); \
  _Pragma("unroll") for (int mf = 0; mf < 4; ++mf) \
    _Pragma("unroll") for (int nf = 0; nf < 2; ++nf) { \
      acc[(MG) * 4 + mf][(NG) * 2 + nf] = __builtin_amdgcn_mfma_f32_16x16x32_bf16( \
          FA0[mf], FB0[nf], acc[(MG) * 4 + mf][(NG) * 2 + nf], 0, 0, 0); \
      acc[(MG) * 4 + mf][(NG) * 2 + nf] = __builtin_amdgcn_mfma_f32_16x16x32_bf16( \
          FA1[mf], FB1[nf], acc[(MG) * 4 + mf][(NG) * 2 + nf], 0, 0, 0); } \
  __builtin_amdgcn_s_setprio(0); \
  __builtin_amdgcn_s_barrier(); \
} while (0)

__global__ __launch_bounds__(512, 2)
void conv_8ph_kernel(const ushort* __restrict__ x2, const ushort* __restrict__ w2,
                     float* __restrict__ out)
{
  __shared__ alignas(16) ushort lds[65536];   // 128 KiB

  const int tid  = threadIdx.x;
  const int lane = tid & 63;
  const int wid  = tid >> 6;    // 0..7
  const int wm   = wid >> 2;    // 0..1  (co 64-half within slot)
  const int wn   = wid & 3;     // 0..3  (pixel 32-quarter within slot)

  const int p0 = blockIdx.x * 256;   // pixel tile (481 tiles; last is half-valid)

  // staging lane geometry (dest is wave-uniform; HW adds lane*16B)
  const int lrow = lane >> 3;              // row within 8-row group
  const int lc   = (lane & 7) ^ lrow;      // pre-swizzled logical chunk
  const int stgu = wid * 1024;             // wave-uniform LDS dest (ushort units)

  // A source offsets: rows h*128 + wid*16 + j*8 + lrow
  int aOff[2][2];
  #pragma unroll
  for (int h = 0; h < 2; ++h)
    #pragma unroll
    for (int j = 0; j < 2; ++j)
      aOff[h][j] = (h * 128 + wid * 16 + j * 8 + lrow) * KTOT + lc * 8;

  // B source offsets, pixel rows clamped for tail tile
  int bOff[2][2];
  #pragma unroll
  for (int h = 0; h < 2; ++h)
    #pragma unroll
    for (int j = 0; j < 2; ++j) {
      int pglob = p0 + h * 128 + wid * 16 + j * 8 + lrow;
      pglob = pglob < NPIX ? pglob : (NPIX - 1);
      const int nimg = pglob / PIXIMG;
      const int prem = pglob - nimg * PIXIMG;
      const int oh   = prem / WO;
      const int ow   = prem - oh * WO;
      bOff[h][j] = ((nimg * HIN + oh) * WIN + ow) * CI + lc * 8;
    }

  // fragment read bases (swizzle folded via XOR with lane&7)
  const int arow = (wm * 64 + (lane & 15)) * 64;
  const int brow = (wn * 32 + (lane & 15)) * 64;
  const int ck0  = ((lane >> 4) ^ (lane & 7)) * 8;
  const int ck1  = ((4 + (lane >> 4)) ^ (lane & 7)) * 8;

  f32x4 acc[8][4];
  #pragma unroll
  for (int i = 0; i < 8; ++i)
    #pragma unroll
    for (int j = 0; j < 4; ++j)
      acc[i][j] = (f32x4){0.f, 0.f, 0.f, 0.f};

  bf16x8 fa0k0[4], fa0k1[4], fa1k0[4], fa1k1[4];
  bf16x8 fb0k0[2], fb0k1[2], fb1k0[2], fb1k1[2];

  // ---- prologue: t0 full (8 loads) + t1's B0,A0 (4 loads) ----
  STAGE_B(0, 0, 0);
  STAGE_A(0, 1, 0);
  STAGE_B(0, 2, 0);
  STAGE_A(0, 3, 0);
  STAGE_B(32768, 0, 1);
  STAGE_A(32768, 1, 1);
  asm volatile("s_waitcnt vmcnt(4)" ::: "memory");   // t0's 4 slots landed
  __builtin_amdgcn_s_barrier();

  int ldb = 0;
  #pragma unroll 1
  for (int t = 0; t < 16; ++t) {
    // p1: read A0+B0; stage t+1's B1,A1 -> other (slots idle since t-1, barrier-drained)
    LOAD_A(fa0k0, fa0k1, ldb, 1);
    LOAD_B(fb0k0, fb0k1, ldb, 0);
    STAGE_B(ldb ^ 32768, 2, t + 1);
    STAGE_A(ldb ^ 32768, 3, t + 1);
    MMA(0, 0, fa0k0, fa0k1, fb0k0, fb0k1);
    // p2: read A1; stage t+2's B0,A0 -> cur.s0/s1 (last read p1, barrier-separated;
    //     B0/A0 data lives in registers now)
    LOAD_A(fa1k0, fa1k1, ldb, 3);
    STAGE_B(ldb, 0, t + 2);
    STAGE_A(ldb, 1, t + 2);
    MMA(1, 0, fa1k0, fa1k1, fb0k0, fb0k1);
    // p3: read B1
    LOAD_B(fb1k0, fb1k1, ldb, 2);
    MMA(0, 1, fa0k0, fa0k1, fb1k0, fb1k1);
    // p4: counted wait -> tile t+1 fully landed (only t+2's 4 loads may remain)
    asm volatile("s_waitcnt vmcnt(4)" ::: "memory");
    MMA(1, 1, fa1k0, fa1k1, fb1k0, fb1k1);
    ldb ^= 32768;
  }
  // ---- t = 16: stage only t17's B1,A1 at p1; drain at p4 ----
  LOAD_A(fa0k0, fa0k1, ldb, 1);
  LOAD_B(fb0k0, fb0k1, ldb, 0);
  STAGE_B(ldb ^ 32768, 2, 17);
  STAGE_A(ldb ^ 32768, 3, 17);
  MMA(0, 0, fa0k0, fa0k1, fb0k0, fb0k1);
  LOAD_A(fa1k0, fa1k1, ldb, 3);
  MMA(1, 0, fa1k0, fa1k1, fb0k0, fb0k1);
  LOAD_B(fb1k0, fb1k1, ldb, 2);
  MMA(0, 1, fa0k0, fa0k1, fb1k0, fb1k1);
  asm volatile("s_waitcnt vmcnt(0)" ::: "memory");    // tile 17 fully landed
  MMA(1, 1, fa1k0, fa1k1, fb1k0, fb1k1);
  ldb ^= 32768;
  // ---- t = 17: no staging, no vm waits ----
  LOAD_A(fa0k0, fa0k1, ldb, 1);
  LOAD_B(fb0k0, fb0k1, ldb, 0);
  MMA(0, 0, fa0k0, fa0k1, fb0k0, fb0k1);
  LOAD_A(fa1k0, fa1k1, ldb, 3);
  MMA(1, 0, fa1k0, fa1k1, fb0k0, fb0k1);
  LOAD_B(fb1k0, fb1k1, ldb, 2);
  MMA(0, 1, fa0k0, fa0k1, fb1k0, fb1k1);
  MMA(1, 1, fa1k0, fa1k1, fb1k0, fb1k1);

  // ---- epilogue: co = MG*128 + wm*64 + mf*16 + (lane>>4)*4 + r ;
  //               pix = p0 + NG*128 + wn*32 + nf*16 + (lane&15)
  #pragma unroll
  for (int ni = 0; ni < 4; ++ni) {
    const int pix = p0 + (ni >> 1) * 128 + wn * 32 + (ni & 1) * 16 + (lane & 15);
    if (pix < NPIX) {
      const int n2  = pix / PIXIMG;
      const int pr2 = pix - n2 * PIXIMG;
      float* ob = out + (size_t)n2 * (CO * PIXIMG) + pr2;
      #pragma unroll
      for (int mi = 0; mi < 8; ++mi) {
        const int cobase = (mi >> 2) * 128 + wm * 64 + (mi & 3) * 16 + ((lane >> 4) * 4);
        float* po = ob + (size_t)cobase * PIXIMG;
        #pragma unroll
        for (int r = 0; r < 4; ++r)
          po[(size_t)r * PIXIMG] = acc[mi][ni][r];
      }
    }
  }
}

// ---------------- fallback (tiny workspace): direct fp32 gather, reg-staged ----------------
__global__ __launch_bounds__(256, 3)
void conv_fallback_kernel(const float* __restrict__ x, const float* __restrict__ wt,
                          float* __restrict__ out)
{
  __shared__ alignas(16) ushort a_lds[128 * 64];
  __shared__ alignas(16) ushort b_lds[128 * 64];

  const int tid  = threadIdx.x;
  const int lane = tid & 63;
  const int wid  = tid >> 6;
  const int wrow = wid >> 1;
  const int wcol = wid & 1;
  const int co0 = blockIdx.x * 128;
  const int p0  = blockIdx.y * 128;

  const int pl    = tid & 127;
  const int kgsel = __builtin_amdgcn_readfirstlane(tid >> 7);
  const int pglob = p0 + pl;
  const int nimg  = pglob / PIXIMG;
  const int prem  = pglob - nimg * PIXIMG;
  const int oh    = prem / WO;
  const int ow    = prem - oh * WO;
  const int xpix  = nimg * XIMG + oh * WIN + ow;

  const int frow_a = wrow * 64 + (lane & 15);
  const int frow_b = wcol * 64 + (lane & 15);
  int aoff[2], boff[2];
  #pragma unroll
  for (int kk = 0; kk < 2; ++kk) {
    const int chk = (kk * 4 + (lane >> 4)) ^ (lane & 7);
    aoff[kk] = frow_a * 64 + chk * 8;
    boff[kk] = frow_b * 64 + chk * 8;
  }

  f32x4 acc[4][4];
  #pragma unroll
  for (int i = 0; i < 4; ++i)
    #pragma unroll
    for (int j = 0; j < 4; ++j)
      acc[i][j] = (f32x4){0.f, 0.f, 0.f, 0.f};

  for (int kt = 0; kt < NKT; ++kt) {
    const int k0 = kt * 64;
    if (kt) __syncthreads();

    #pragma unroll
    for (int it = 0; it < 4; ++it) {
      const int kg = kgsel + it * 2;
      uint pk[4];
      #pragma unroll
      for (int j = 0; j < 8; ++j) {
        const int k  = k0 + kg * 8 + j;
        const int ci = k / 9;
        const int rs = k - ci * 9;
        const int r  = rs / 3;
        const int s  = rs - r * 3;
        const ushort u = f2bf(x[xpix + ci * (HIN * WIN) + r * WIN + s]);
        if (j & 1) pk[j >> 1] |= ((uint)u) << 16;
        else       pk[j >> 1]  = (uint)u;
      }
      uint4v q = {pk[0], pk[1], pk[2], pk[3]};
      *reinterpret_cast<uint4v*>(&b_lds[pl * 64 + ((kg ^ (pl & 7)) * 8)]) = q;
    }

    #pragma unroll
    for (int i = 0; i < 8; ++i) {
      const int id  = i * 256 + tid;
      const int row = id >> 4;
      const int c4  = id & 15;
      const float4 v = *reinterpret_cast<const float4*>(
          wt + (size_t)(co0 + row) * KTOT + k0 + c4 * 4);
      uint2v q;
      q[0] = (uint)f2bf(v.x) | ((uint)f2bf(v.y) << 16);
      q[1] = (uint)f2bf(v.z) | ((uint)f2bf(v.w) << 16);
      *reinterpret_cast<uint2v*>(
          &a_lds[row * 64 + (((c4 >> 1) ^ (row & 7)) * 8) + (c4 & 1) * 4]) = q;
    }

    __syncthreads();

    #pragma unroll
    for (int kk = 0; kk < 2; ++kk) {
      bf16x8 af[4], bb[4];
      #pragma unroll
      for (int mi = 0; mi < 4; ++mi)
        af[mi] = *reinterpret_cast<const bf16x8*>(&a_lds[aoff[kk] + mi * (16 * 64)]);
      #pragma unroll
      for (int ni = 0; ni < 4; ++ni)
        bb[ni] = *reinterpret_cast<const bf16x8*>(&b_lds[boff[kk] + ni * (16 * 64)]);
      #pragma unroll
      for (int mi = 0; mi < 4; ++mi)
        #pragma unroll
        for (int ni = 0; ni < 4; ++ni)
          acc[mi][ni] = __builtin_amdgcn_mfma_f32_16x16x32_bf16(af[mi], bb[ni], acc[mi][ni], 0, 0, 0);
    }
  }

  #pragma unroll
  for (int ni = 0; ni < 4; ++ni) {
    const int pix = p0 + wcol * 64 + ni * 16 + (lane & 15);
    const int n2  = pix / PIXIMG;
    const int pr2 = pix - n2 * PIXIMG;
    float* ob = out + (size_t)n2 * (CO * PIXIMG) + pr2
                    + (size_t)(co0 + wrow * 64 + ((lane >> 4) * 4)) * PIXIMG;
    #pragma unroll
    for (int mi = 0; mi < 4; ++mi) {
      float* po = ob + (size_t)mi * (16 * PIXIMG);
      #pragma unroll
      for (int r = 0; r < 4; ++r)
        po[(size_t)r * PIXIMG] = acc[mi][ni][r];
    }
  }
}

extern "C" void kernel_launch(void* const* d_in, const int* in_sizes, int n_in,
                              void* d_out, int out_size, void* d_ws, size_t ws_size,
                              hipStream_t stream) {
  const float* x  = (const float*)d_in[0];
  const float* wt = (const float*)d_in[1];
  float* out = (float*)d_out;

  ushort* w2 = (ushort*)d_ws;
  ushort* x2 = (ushort*)((char*)d_ws + 589824);

  const size_t need = 589824 + (size_t)NB * XIMG * 2;   // ~34.1 MB

  if (ws_size >= need) {
    repack_w_kernel<<<dim3(CO), dim3(256), 0, stream>>>(wt, w2);
    repack_x_kernel<<<dim3(HIN, NB), dim3(256), 0, stream>>>(x, x2);
    conv_8ph_kernel<<<dim3(481), dim3(512), 0, stream>>>(x2, w2, out);
  } else {
    conv_fallback_kernel<<<dim3(CO / 128, NPIX / 128), dim3(256), 0, stream>>>(x, wt, out);
  }
}